// Round 1
// baseline (346.591 us; speedup 1.0000x reference)
//
#include <hip/hip_runtime.h>
#include <hip/hip_bf16.h>

// Problem constants
#define B_SIZE 8192
#define D_SIZE 2048
#define C_SIZE 128
#define N_INNER 255   // 2^8 - 1
#define N_LEAF 256

// ---------------- K0: softmax over leaf_params rows -> Q, logQ ----------------
__global__ __launch_bounds__(128) void softmax_kernel(
    const float* __restrict__ lp, float* __restrict__ Q, float* __restrict__ logQ)
{
    int row = blockIdx.x;
    int t = threadIdx.x;
    __shared__ float red[128];
    float v = lp[row * C_SIZE + t];
    red[t] = v; __syncthreads();
    for (int s = 64; s > 0; s >>= 1) { if (t < s) red[t] = fmaxf(red[t], red[t + s]); __syncthreads(); }
    float mx = red[0]; __syncthreads();
    float e = expf(v - mx);
    red[t] = e; __syncthreads();
    for (int s = 64; s > 0; s >>= 1) { if (t < s) red[t] += red[t + s]; __syncthreads(); }
    float sum = red[0];
    Q[row * C_SIZE + t] = e / sum;
    logQ[row * C_SIZE + t] = (v - mx) - logf(sum);
}

// ---------------- K1: p = sigmoid(beta * (x @ W^T + b)) ----------------
// fp32 tiled GEMM, 64x64 tile, TK=16, 256 threads, 4x4 microtile per thread.
#define TM 64
#define TN 64
#define TK 16
__global__ __launch_bounds__(256) void gemm_sigmoid(
    const float* __restrict__ x, const float* __restrict__ W,
    const float* __restrict__ b, const float* __restrict__ beta,
    float* __restrict__ p)
{
    __shared__ float As[TK][TM + 1];
    __shared__ float Bs[TK][TN + 1];
    int bm = blockIdx.x * TM;
    int bn = blockIdx.y * TN;
    int t = threadIdx.x;
    int tx = t & 15;       // 0..15 (cols)
    int ty = t >> 4;       // 0..15 (rows)
    int lr = t >> 2;       // 0..63: row index for cooperative loads
    int lk = (t & 3) * 4;  // 0,4,8,12: k offset for float4 loads

    float acc[4][4] = {};

    for (int k0 = 0; k0 < D_SIZE; k0 += TK) {
        float4 a = *(const float4*)(x + (size_t)(bm + lr) * D_SIZE + k0 + lk);
        int n = bn + lr;
        float4 w = make_float4(0.f, 0.f, 0.f, 0.f);
        if (n < N_INNER) w = *(const float4*)(W + (size_t)n * D_SIZE + k0 + lk);
        __syncthreads();
        As[lk + 0][lr] = a.x; As[lk + 1][lr] = a.y; As[lk + 2][lr] = a.z; As[lk + 3][lr] = a.w;
        Bs[lk + 0][lr] = w.x; Bs[lk + 1][lr] = w.y; Bs[lk + 2][lr] = w.z; Bs[lk + 3][lr] = w.w;
        __syncthreads();
        #pragma unroll
        for (int k = 0; k < TK; ++k) {
            float av[4], bv[4];
            #pragma unroll
            for (int i = 0; i < 4; ++i) av[i] = As[k][ty * 4 + i];
            #pragma unroll
            for (int j = 0; j < 4; ++j) bv[j] = Bs[k][tx * 4 + j];
            #pragma unroll
            for (int i = 0; i < 4; ++i)
                #pragma unroll
                for (int j = 0; j < 4; ++j)
                    acc[i][j] = fmaf(av[i], bv[j], acc[i][j]);
        }
    }

    #pragma unroll
    for (int i = 0; i < 4; ++i) {
        int row = bm + ty * 4 + i;
        #pragma unroll
        for (int j = 0; j < 4; ++j) {
            int col = bn + tx * 4 + j;
            if (col < N_INNER) {
                float z = beta[col] * (acc[i][j] + b[col]);
                p[(size_t)row * N_INNER + col] = 1.0f / (1.0f + expf(-z));
            }
        }
    }
}

// ---------------- K2: path products, penalties, loss, argmax + output gather ----------------
#define ROWS_PER_BLOCK 8
__global__ __launch_bounds__(256) void path_kernel(
    const float* __restrict__ p, const int* __restrict__ target,
    const float* __restrict__ Q, const float* __restrict__ logQ,
    float* __restrict__ g_num, float* __restrict__ g_den, float* __restrict__ g_loss,
    float* __restrict__ out)
{
    __shared__ float p_row[256];
    __shared__ float red[256];
    __shared__ float rval[256];
    __shared__ int   ridx[256];
    __shared__ float s_num[128], s_den[128];
    __shared__ int   s_leaf;

    int t = threadIdx.x;
    int row0 = blockIdx.x * ROWS_PER_BLOCK;
    if (t < 128) { s_num[t] = 0.f; s_den[t] = 0.f; }
    float loss_acc = 0.f;

    for (int r = 0; r < ROWS_PER_BLOCK; ++r) {
        int row = row0 + r;
        __syncthreads();
        if (t < N_INNER) p_row[t] = p[(size_t)row * N_INNER + t];
        __syncthreads();

        // leaf path probability: product of 8 ancestor gates
        float pl = 1.f;
        #pragma unroll
        for (int d = 0; d < 8; ++d) {
            int node = (1 << d) - 1 + (t >> (8 - d));
            int bit = (t >> (7 - d)) & 1;
            float pv = p_row[node];
            pl *= bit ? pv : (1.f - pv);
        }

        // penalty partials for inner nodes at depths 0..6 (array index 0..126)
        if (t < 127) {
            int h = t + 1;                 // 1-indexed heap
            int d = 31 - __clz(h);         // depth
            float pp = 1.f;
            for (int e = 0; e < d; ++e) {
                int ha = h >> (d - e);
                int bit = (h >> (d - 1 - e)) & 1;
                float pv = p_row[ha - 1];
                pp *= bit ? pv : (1.f - pv);
            }
            s_num[t] += p_row[t] * pp;
            s_den[t] += pp;
        }

        // loss term + argmax over 256 leaves
        int tgt = target[row];
        red[t] = pl * logQ[t * C_SIZE + tgt];
        rval[t] = pl; ridx[t] = t;
        __syncthreads();
        for (int s = 128; s > 0; s >>= 1) {
            if (t < s) {
                red[t] += red[t + s];
                float v2 = rval[t + s];
                if (v2 > rval[t] || (v2 == rval[t] && ridx[t + s] < ridx[t])) {
                    rval[t] = v2; ridx[t] = ridx[t + s];
                }
            }
            __syncthreads();
        }
        if (t == 0) { loss_acc += red[0]; s_leaf = ridx[0]; }
        __syncthreads();
        int leaf = s_leaf;
        if (t < C_SIZE) out[1 + (size_t)row * C_SIZE + t] = Q[leaf * C_SIZE + t];
    }

    __syncthreads();
    if (t < 127) {
        atomicAdd(&g_num[t], s_num[t]);
        atomicAdd(&g_den[t], s_den[t]);
    }
    if (t == 0) atomicAdd(g_loss, loss_acc);
}

// ---------------- K3: finalize total ----------------
__global__ __launch_bounds__(128) void finalize_kernel(
    const float* __restrict__ g_num, const float* __restrict__ g_den,
    const float* __restrict__ g_loss, float* __restrict__ out)
{
    __shared__ float red[128];
    int t = threadIdx.x;
    float term = 0.f;
    if (t < 127) {
        int d = 31 - __clz(t + 1);
        float lam = 0.1f * exp2f(-(float)(d + 1));
        float pen = g_num[t] / g_den[t];
        term = lam * 0.5f * (logf(pen) + logf(1.f - pen));
    }
    red[t] = term; __syncthreads();
    for (int s = 64; s > 0; s >>= 1) { if (t < s) red[t] += red[t + s]; __syncthreads(); }
    if (t == 0) out[0] = -(g_loss[0] / (float)B_SIZE) - red[0];
}

extern "C" void kernel_launch(void* const* d_in, const int* in_sizes, int n_in,
                              void* d_out, int out_size, void* d_ws, size_t ws_size,
                              hipStream_t stream)
{
    const float* x    = (const float*)d_in[0];
    const int*   tgt  = (const int*)d_in[1];
    const float* W    = (const float*)d_in[2];
    const float* b    = (const float*)d_in[3];
    const float* beta = (const float*)d_in[4];
    const float* lp   = (const float*)d_in[5];
    float* out = (float*)d_out;

    // ws layout (floats): [0:128) pen_num, [128:256) pen_den, [256] loss, pad to 512,
    // then p (8192*255), Q (256*128), logQ (256*128)
    float* g_acc = (float*)d_ws;
    float* p     = g_acc + 512;
    float* Q     = p + (size_t)B_SIZE * N_INNER;
    float* logQ  = Q + (size_t)N_LEAF * C_SIZE;

    hipMemsetAsync(d_ws, 0, 512 * sizeof(float), stream);

    softmax_kernel<<<N_LEAF, 128, 0, stream>>>(lp, Q, logQ);

    dim3 ggrid(B_SIZE / TM, (N_LEAF + TN - 1) / TN);
    gemm_sigmoid<<<ggrid, 256, 0, stream>>>(x, W, b, beta, p);

    path_kernel<<<B_SIZE / ROWS_PER_BLOCK, 256, 0, stream>>>(
        p, tgt, Q, logQ, g_acc, g_acc + 128, g_acc + 256, out);

    finalize_kernel<<<1, 128, 0, stream>>>(g_acc, g_acc + 128, g_acc + 256, out);
}

// Round 3
// 216.009 us; speedup vs baseline: 1.6045x; 1.6045x over previous
//
#include <hip/hip_runtime.h>
#include <hip/hip_bf16.h>
#include <hip/hip_fp16.h>
#include <stdint.h>

#define B_SIZE 8192
#define D_SIZE 2048
#define C_SIZE 128
#define N_INNER 255
#define N_LEAF 256
#define NPAD 256

typedef _Float16 half8 __attribute__((ext_vector_type(8)));
typedef __fp16 pk16x2 __attribute__((ext_vector_type(2)));   // return type of cvt_pkrtz
typedef float f32x4 __attribute__((ext_vector_type(4)));
typedef unsigned short u16;

// ---- fp32 -> (hi,lo) fp16 split, packed pairs ----
__device__ inline uint32_t pkh(float a, float b) {
    pk16x2 h = __builtin_amdgcn_cvt_pkrtz(a, b);
    return __builtin_bit_cast(uint32_t, h);
}
__device__ inline void split4(const float4 v, uint2& hi, uint2& lo) {
    pk16x2 a01 = __builtin_amdgcn_cvt_pkrtz(v.x, v.y);
    pk16x2 a23 = __builtin_amdgcn_cvt_pkrtz(v.z, v.w);
    float r0 = v.x - (float)a01[0];
    float r1 = v.y - (float)a01[1];
    float r2 = v.z - (float)a23[0];
    float r3 = v.w - (float)a23[1];
    hi = make_uint2(__builtin_bit_cast(uint32_t, a01), __builtin_bit_cast(uint32_t, a23));
    lo = make_uint2(pkh(r0, r1), pkh(r2, r3));
}

// ---------------- K0: softmax over leaf_params rows -> Q, logQ ----------------
__global__ __launch_bounds__(128) void softmax_kernel(
    const float* __restrict__ lp, float* __restrict__ Q, float* __restrict__ logQ)
{
    int row = blockIdx.x;
    int t = threadIdx.x;
    __shared__ float red[128];
    float v = lp[row * C_SIZE + t];
    red[t] = v; __syncthreads();
    for (int s = 64; s > 0; s >>= 1) { if (t < s) red[t] = fmaxf(red[t], red[t + s]); __syncthreads(); }
    float mx = red[0]; __syncthreads();
    float e = expf(v - mx);
    red[t] = e; __syncthreads();
    for (int s = 64; s > 0; s >>= 1) { if (t < s) red[t] += red[t + s]; __syncthreads(); }
    float sum = red[0];
    Q[row * C_SIZE + t] = e / sum;
    logQ[row * C_SIZE + t] = (v - mx) - logf(sum);
}

// ---------------- K1: z_part[kz] = x @ W^T partial sums (fp16-split MFMA) ----------------
#define BM 64
#define BN 128
#define BK 64
#define KSPLIT 2
#define LDK 72   // u16 per LDS row: 64 k + 8 pad (144 B stride -> max 2-way bank alias = free)

__global__ __launch_bounds__(256, 2) void gemm_split_f16(
    const float* __restrict__ x, const float* __restrict__ W,
    float* __restrict__ zp)
{
    __shared__ __align__(16) u16 sAh[BM * LDK];
    __shared__ __align__(16) u16 sAl[BM * LDK];
    __shared__ __align__(16) u16 sBh[BN * LDK];
    __shared__ __align__(16) u16 sBl[BN * LDK];

    const int t = threadIdx.x;
    const int m0 = blockIdx.x * BM;
    const int n0 = blockIdx.y * BN;
    const int kz = blockIdx.z;
    const int lane = t & 63;
    const int w = t >> 6;
    const int wm = w & 1, wn = w >> 1;      // 2x2 wave grid; wave tile 32(M) x 64(N)
    const int lr = lane & 15, lq = lane >> 4;

    f32x4 zero4 = {0.f, 0.f, 0.f, 0.f};
    f32x4 acc[2][4];
    #pragma unroll
    for (int mt = 0; mt < 2; ++mt)
        #pragma unroll
        for (int nt = 0; nt < 4; ++nt) acc[mt][nt] = zero4;

    const int kbase0 = kz * (D_SIZE / KSPLIT);
    for (int kt = 0; kt < D_SIZE / KSPLIT; kt += BK) {
        const int kb = kbase0 + kt;
        __syncthreads();
        // stage A: 64 rows x 64 k = 1024 float4, 4 per thread
        #pragma unroll
        for (int i = 0; i < 4; ++i) {
            int idx = t + 256 * i;
            int row = idx >> 4, kq = idx & 15;
            float4 v = *(const float4*)(x + (size_t)(m0 + row) * D_SIZE + kb + kq * 4);
            uint2 hi, lo; split4(v, hi, lo);
            *(uint2*)&sAh[row * LDK + kq * 4] = hi;
            *(uint2*)&sAl[row * LDK + kq * 4] = lo;
        }
        // stage B: 128 rows x 64 k = 2048 float4, 8 per thread (row>=255 -> zeros)
        #pragma unroll
        for (int i = 0; i < 8; ++i) {
            int idx = t + 256 * i;
            int row = idx >> 4, kq = idx & 15;
            int ng = n0 + row;
            float4 v = make_float4(0.f, 0.f, 0.f, 0.f);
            if (ng < N_INNER) v = *(const float4*)(W + (size_t)ng * D_SIZE + kb + kq * 4);
            uint2 hi, lo; split4(v, hi, lo);
            *(uint2*)&sBh[row * LDK + kq * 4] = hi;
            *(uint2*)&sBl[row * LDK + kq * 4] = lo;
        }
        __syncthreads();
        #pragma unroll
        for (int ks = 0; ks < 2; ++ks) {
            half8 ah[2], al[2], bh[4], bl[4];
            #pragma unroll
            for (int mt = 0; mt < 2; ++mt) {
                int off = (wm * 32 + mt * 16 + lr) * LDK + ks * 32 + lq * 8;
                ah[mt] = *(const half8*)&sAh[off];
                al[mt] = *(const half8*)&sAl[off];
            }
            #pragma unroll
            for (int nt = 0; nt < 4; ++nt) {
                int off = (wn * 64 + nt * 16 + lr) * LDK + ks * 32 + lq * 8;
                bh[nt] = *(const half8*)&sBh[off];
                bl[nt] = *(const half8*)&sBl[off];
            }
            #pragma unroll
            for (int mt = 0; mt < 2; ++mt)
                #pragma unroll
                for (int nt = 0; nt < 4; ++nt) {
                    acc[mt][nt] = __builtin_amdgcn_mfma_f32_16x16x32_f16(ah[mt], bh[nt], acc[mt][nt], 0, 0, 0);
                    acc[mt][nt] = __builtin_amdgcn_mfma_f32_16x16x32_f16(ah[mt], bl[nt], acc[mt][nt], 0, 0, 0);
                    acc[mt][nt] = __builtin_amdgcn_mfma_f32_16x16x32_f16(al[mt], bh[nt], acc[mt][nt], 0, 0, 0);
                }
        }
    }

    float* zout = zp + (size_t)kz * B_SIZE * NPAD;
    #pragma unroll
    for (int mt = 0; mt < 2; ++mt)
        #pragma unroll
        for (int nt = 0; nt < 4; ++nt) {
            int gn = n0 + wn * 64 + nt * 16 + lr;
            if (gn < N_INNER) {
                #pragma unroll
                for (int r = 0; r < 4; ++r) {
                    int gm = m0 + wm * 32 + mt * 16 + lq * 4 + r;
                    zout[(size_t)gm * NPAD + gn] = acc[mt][nt][r];
                }
            }
        }
}

// ---------------- K2: fused sigmoid + paths + penalties + loss + argmax gather ----------------
// 256 threads = 4 waves; each wave owns one row at a time (wave-local shuffles only).
__global__ __launch_bounds__(256) void path_kernel(
    const float* __restrict__ z0, const float* __restrict__ z1,
    const int* __restrict__ target, const float* __restrict__ bvec,
    const float* __restrict__ beta, const float* __restrict__ Q,
    const float* __restrict__ logQ,
    float* __restrict__ g_num, float* __restrict__ g_den,
    float* __restrict__ g_loss, float* __restrict__ out)
{
    __shared__ float pbuf[4][256];
    const int t = threadIdx.x, w = t >> 6, lane = t & 63;
    const int n2 = lane + 64;
    float num0 = 0.f, den0 = 0.f, num1 = 0.f, den1 = 0.f, loss = 0.f;

    for (int i = 0; i < 8; ++i) {
        int r = blockIdx.x * 32 + i * 4 + w;
        __syncthreads();   // protect pbuf reuse across iterations
        #pragma unroll
        for (int j = 0; j < 4; ++j) {
            int c = lane + 64 * j;
            float pv = 0.f;
            if (c < N_INNER) {
                float z = z0[(size_t)r * NPAD + c] + z1[(size_t)r * NPAD + c];
                pv = 1.f / (1.f + expf(-beta[c] * (z + bvec[c])));
            }
            pbuf[w][c] = pv;
        }
        __syncthreads();

        int tg = target[r];
        float lsum = 0.f, bestV = -1.f;
        int bestI = 0;
        #pragma unroll
        for (int j = 0; j < 4; ++j) {
            int leaf = lane + 64 * j;
            float pl = 1.f;
            #pragma unroll
            for (int d = 0; d < 8; ++d) {
                int node = (1 << d) - 1 + (leaf >> (8 - d));
                int bit = (leaf >> (7 - d)) & 1;
                float pv = pbuf[w][node];
                pl *= bit ? pv : (1.f - pv);
            }
            lsum += pl * logQ[leaf * C_SIZE + tg];
            if (pl > bestV || (pl == bestV && leaf < bestI)) { bestV = pl; bestI = leaf; }
        }
        // penalty partials: node = lane (0..63) and lane+64 (64..126)
        {
            int h = lane + 1; int d = 31 - __clz(h);
            float pp = 1.f;
            for (int e = 0; e < d; ++e) {
                int ha = h >> (d - e);
                int bit = (h >> (d - 1 - e)) & 1;
                float pv = pbuf[w][ha - 1];
                pp *= bit ? pv : (1.f - pv);
            }
            num0 += pbuf[w][lane] * pp; den0 += pp;
        }
        if (n2 < 127) {
            int h = n2 + 1; int d = 31 - __clz(h);
            float pp = 1.f;
            for (int e = 0; e < d; ++e) {
                int ha = h >> (d - e);
                int bit = (h >> (d - 1 - e)) & 1;
                float pv = pbuf[w][ha - 1];
                pp *= bit ? pv : (1.f - pv);
            }
            num1 += pbuf[w][n2] * pp; den1 += pp;
        }
        // wave reductions (sum + argmax with lowest-index tie-break)
        #pragma unroll
        for (int m = 1; m < 64; m <<= 1) {
            lsum += __shfl_xor(lsum, m, 64);
            float ov = __shfl_xor(bestV, m, 64);
            int   oi = __shfl_xor(bestI, m, 64);
            if (ov > bestV || (ov == bestV && oi < bestI)) { bestV = ov; bestI = oi; }
        }
        loss += lsum;
        out[1 + (size_t)r * C_SIZE + lane]      = Q[bestI * C_SIZE + lane];
        out[1 + (size_t)r * C_SIZE + lane + 64] = Q[bestI * C_SIZE + lane + 64];
    }

    atomicAdd(&g_num[lane], num0);
    atomicAdd(&g_den[lane], den0);
    if (n2 < 127) { atomicAdd(&g_num[n2], num1); atomicAdd(&g_den[n2], den1); }
    if (lane == 0) atomicAdd(g_loss, loss);
}

// ---------------- K3: finalize total ----------------
__global__ __launch_bounds__(128) void finalize_kernel(
    const float* __restrict__ g_num, const float* __restrict__ g_den,
    const float* __restrict__ g_loss, float* __restrict__ out)
{
    __shared__ float red[128];
    int t = threadIdx.x;
    float term = 0.f;
    if (t < 127) {
        int d = 31 - __clz(t + 1);
        float lam = 0.1f * exp2f(-(float)(d + 1));
        float pen = g_num[t] / g_den[t];
        term = lam * 0.5f * (logf(pen) + logf(1.f - pen));
    }
    red[t] = term; __syncthreads();
    for (int s = 64; s > 0; s >>= 1) { if (t < s) red[t] += red[t + s]; __syncthreads(); }
    if (t == 0) out[0] = -(g_loss[0] / (float)B_SIZE) - red[0];
}

extern "C" void kernel_launch(void* const* d_in, const int* in_sizes, int n_in,
                              void* d_out, int out_size, void* d_ws, size_t ws_size,
                              hipStream_t stream)
{
    const float* x    = (const float*)d_in[0];
    const int*   tgt  = (const int*)d_in[1];
    const float* W    = (const float*)d_in[2];
    const float* b    = (const float*)d_in[3];
    const float* beta = (const float*)d_in[4];
    const float* lp   = (const float*)d_in[5];
    float* out = (float*)d_out;

    // ws layout (floats): [0:128) pen_num, [128:256) pen_den, [256] loss, pad to 512,
    // then z0 (8192*256), z1 (8192*256), Q (256*128), logQ (256*128)  ~= 17 MB
    float* g_acc = (float*)d_ws;
    float* z0    = g_acc + 512;
    float* z1    = z0 + (size_t)B_SIZE * NPAD;
    float* Q     = z1 + (size_t)B_SIZE * NPAD;
    float* logQ  = Q + (size_t)N_LEAF * C_SIZE;

    (void)hipMemsetAsync(d_ws, 0, 512 * sizeof(float), stream);

    softmax_kernel<<<N_LEAF, 128, 0, stream>>>(lp, Q, logQ);

    dim3 ggrid(B_SIZE / BM, N_LEAF / BN, KSPLIT);   // 128 x 2 x 2 = 512 blocks
    gemm_split_f16<<<ggrid, 256, 0, stream>>>(x, W, z0);

    path_kernel<<<B_SIZE / 32, 256, 0, stream>>>(
        z0, z1, tgt, b, beta, Q, logQ,
        g_acc, g_acc + 128, g_acc + 256, out);

    finalize_kernel<<<1, 128, 0, stream>>>(g_acc, g_acc + 128, g_acc + 256, out);
}